// Round 24
// baseline (175.406 us; speedup 1.0000x reference)
//
#include <hip/hip_runtime.h>
#include <hip/hip_bf16.h>
#include <math.h>

#define Fdim 128
#define CAP 32
// Fixed softmax shift: p >= 0 always (relu'd Q,K); p <= ~70 worst case.
#define SM_SHIFT 20.0f

typedef __attribute__((ext_vector_type(8))) short bf16x8;
typedef __attribute__((ext_vector_type(4))) float f32x4;

__device__ __forceinline__ unsigned short f2bf(float x) {
    __hip_bfloat16 h = __float2bfloat16(x);
    return *(unsigned short*)&h;
}
__device__ __forceinline__ unsigned int pk2bf(float a, float b) {
    return (unsigned int)f2bf(a) | ((unsigned int)f2bf(b) << 16);
}
__device__ __forceinline__ float bflo(unsigned int u) {
    unsigned int b = u << 16;
    return *(float*)&b;
}
__device__ __forceinline__ float bfhi(unsigned int u) {
    unsigned int b = u & 0xffff0000u;
    return *(float*)&b;
}

// ---------------- Weight prep: WT[c][k] bf16, c in [0,192) = q|k|v cols ----------------
__global__ void k_wt(const float* __restrict__ wq, const float* __restrict__ wk,
                     const float* __restrict__ wv, unsigned short* __restrict__ WT) {
    int t = blockIdx.x * blockDim.x + threadIdx.x;
    if (t >= 192 * Fdim) return;
    int c = t >> 7, k = t & 127;
    float v = (c < 64) ? wq[k * 64 + c]
            : (c < 128) ? wk[k * 64 + (c - 64)]
                        : wv[k * 64 + (c - 128)];
    WT[t] = f2bf(v);
}

// ---------------- Role-split kernel: GEMM blocks | scatter+zero blocks ----------------
// Blocks [0, ngemm): MFMA node-0 GEMM only (short critical path).
// Blocks [ngemm, grid): zero-slice + partition-filtered adjacency scatter only.
// The two roles co-schedule on the CUs -> time = max(GEMM, scatter), not sum.
__global__ __launch_bounds__(256) void k_node0adj(
    const float* __restrict__ x,
    const unsigned short* __restrict__ WT,
    const float* __restrict__ bq, const float* __restrict__ bk,
    float* __restrict__ Q0, unsigned int* __restrict__ KV0,
    const int* __restrict__ row, const int* __restrict__ col,
    int* __restrict__ cnt, unsigned short* __restrict__ adj,
    unsigned int* __restrict__ spill, int* __restrict__ spill_cnt,
    float4* __restrict__ extra_zero, int extra_zero_q,
    int E_, int Etot, int n, int ngemm) {
    int t = threadIdx.x;
    if (blockIdx.x >= ngemm) {
        // ================= scatter role =================
        int bid2 = blockIdx.x - ngemm;
        int nsb = gridDim.x - ngemm;
        // --- zero the spill-extra region ---
        {
            int stride = nsb * 256;
            float4 z = make_float4(0.f, 0.f, 0.f, 0.f);
            for (int i = bid2 * 256 + t; i < extra_zero_q; i += stride)
                extra_zero[i] = z;
        }
        // --- adjacency: quarter-streams, partition-filtered (single-XCD lines) ---
        int p = bid2 & 7;
        int gb = bid2 >> 3;
        int ngb = nsb >> 3;
        if (gb < ngb) {
            int quarter = (Etot + 3) >> 2;
            int stride = ngb * 256;
            for (int base = gb * 256 + t; base < quarter; base += stride) {
                #pragma unroll
                for (int qd = 0; qd < 4; ++qd) {
                    int e = base + qd * quarter;
                    if (e < Etot) {
                        int r, c;
                        if (e < E_) { r = row[e]; c = col[e]; } else { r = e - E_; c = r; }
                        if (((r >> 4) & 7) == p) {
                            int pos = atomicAdd(&cnt[r], 1);
                            if (pos < CAP) {
                                adj[(size_t)r * CAP + pos] = (unsigned short)c;
                            } else {
                                int sp = atomicAdd(spill_cnt, 1);
                                spill[sp] = ((unsigned int)r << 16) | (unsigned int)c;
                            }
                        }
                    }
                }
            }
        }
        return;
    }
    // ================= GEMM role =================
    int wv_ = t >> 6;
    int ln = t & 63;
    int rowbase = blockIdx.x * 64 + wv_ * 16;
    if (rowbase >= n) return;
    int cl = ln & 15;
    int kgrp = (ln >> 4) * 8;
    int arow = rowbase + cl;
    int arowc = min(arow, n - 1);
    f32x4 acc[12];
    #pragma unroll
    for (int i = 0; i < 12; ++i) acc[i] = (f32x4)(0.f);
    #pragma unroll
    for (int ks = 0; ks < 4; ++ks) {
        int k0 = ks * 32 + kgrp;
        const float4* xp = (const float4*)(x + (size_t)arowc * Fdim + k0);
        float4 xa = xp[0], xb = xp[1];
        union { unsigned int u[4]; bf16x8 v; } af;
        af.u[0] = pk2bf(xa.x, xa.y);
        af.u[1] = pk2bf(xa.z, xa.w);
        af.u[2] = pk2bf(xb.x, xb.y);
        af.u[3] = pk2bf(xb.z, xb.w);
        #pragma unroll
        for (int tt = 0; tt < 12; ++tt) {
            bf16x8 bf = *(const bf16x8*)(WT + (size_t)(tt * 16 + cl) * Fdim + k0);
            acc[tt] = __builtin_amdgcn_mfma_f32_16x16x32_bf16(af.v, bf, acc[tt], 0, 0, 0);
        }
    }
    int rgrp = (ln >> 4) * 4;
    #pragma unroll
    for (int r = 0; r < 4; ++r) {
        int node = rowbase + rgrp + r;
        if (node < n) {
            #pragma unroll
            for (int tq = 0; tq < 4; ++tq) {
                float q = fmaxf(acc[tq][r] + bq[tq * 16 + cl], 0.f);
                Q0[(size_t)node * 64 + tq * 16 + cl] = q;
            }
            #pragma unroll
            for (int tk = 0; tk < 4; ++tk) {
                float kk = fmaxf(acc[4 + tk][r] + bk[tk * 16 + cl], 0.f);
                float vv = acc[8 + tk][r];
                KV0[(size_t)node * 64 + tk * 16 + cl] =
                    (unsigned int)f2bf(kk) | ((unsigned int)f2bf(vv) << 16);
            }
        }
    }
}

// ---------------- Spill fixup, layer 0: one wave per spilled edge ----------------
__global__ void k_spill0(const int* __restrict__ spill_cnt,
                         const unsigned int* __restrict__ spill,
                         const float* __restrict__ Q0,
                         const unsigned int* __restrict__ KV0,
                         float* __restrict__ extra0) {
    int sc = *spill_cnt;
    int widx = (blockIdx.x * blockDim.x + threadIdx.x) >> 6;
    int nw = (gridDim.x * blockDim.x) >> 6;
    int j = threadIdx.x & 63;
    for (int i = widx; i < sc; i += nw) {
        unsigned int pc = spill[i];
        int r = pc >> 16, c = pc & 0xFFFF;
        float q = Q0[(size_t)r * 64 + j] * 0.35355339059327373f;
        unsigned int kv = KV0[(size_t)c * 64 + j];
        float p = q * bflo(kv);
        #pragma unroll
        for (int off = 1; off < 8; off <<= 1) p += __shfl_xor(p, off);
        float w = __expf(p - SM_SHIFT);
        atomicAdd(&extra0[(size_t)r * 72 + 8 + j], w * bfhi(kv));
        if ((j & 7) == 0) atomicAdd(&extra0[(size_t)r * 72 + (j >> 3)], w);
    }
}

// ---------------- Spill fixup, layer 1 ----------------
__global__ void k_spill1(const int* __restrict__ spill_cnt,
                         const unsigned int* __restrict__ spill,
                         const float* __restrict__ Q1, const float* __restrict__ K1,
                         const unsigned short* __restrict__ V1u,
                         float* __restrict__ extra1) {
    int sc = *spill_cnt;
    int widx = (blockIdx.x * blockDim.x + threadIdx.x) >> 6;
    int nw = (gridDim.x * blockDim.x) >> 6;
    int j = threadIdx.x & 63;
    for (int i = widx; i < sc; i += nw) {
        unsigned int pc = spill[i];
        int r = pc >> 16, c = pc & 0xFFFF;
        float w = __expf(Q1[r] * K1[c] - SM_SHIFT);
        if (j < 40) {
            float v = bflo((unsigned int)V1u[(size_t)c * 40 + j]);
            atomicAdd(&extra1[(size_t)r * 44 + 4 + j], w * v);
        } else if (j == 63) {
            atomicAdd(&extra1[(size_t)r * 44], w);
        }
    }
}

// ---------------- Layer-0 fused: 16-lanes-per-edge uint4 gathers ----------------
__global__ __launch_bounds__(256) void k_fuse0(
    const int* __restrict__ cnt, const unsigned short* __restrict__ adj,
    const float* __restrict__ Q0, const unsigned int* __restrict__ KV0,
    const float* __restrict__ extra0, const int* __restrict__ spillc,
    const float* __restrict__ b0,
    const float* __restrict__ wq1, const float* __restrict__ bq1,
    const float* __restrict__ wk1, const float* __restrict__ bk1,
    const float* __restrict__ wv1,
    float* __restrict__ Q1, float* __restrict__ K1,
    unsigned short* __restrict__ V1u, int n) {
    __shared__ float hs[8][64];
    int wid = threadIdx.x >> 6;
    int lane = threadIdx.x & 63;
    int sub = lane >> 5;
    int l = lane & 31;
    int sl = l >> 4;           // edge slot within half
    int dl = l & 15;           // dim-lane: dims 4dl..4dl+3
    int half = wid * 2 + sub;
    int node = blockIdx.x * 8 + half;
    if (node >= n) return;
    const float SC = 0.35355339059327373f;
    float4 q4 = ((const float4*)(Q0 + (size_t)node * 64))[dl];
    q4.x *= SC; q4.y *= SC; q4.z *= SC; q4.w *= SC;
    int end = min(cnt[node], CAP);
    int myadj = (int)adj[(size_t)node * CAP + l];
    int sbase = sub * 32;
    float s = 0.f;
    float accx = 0.f, accy = 0.f, accz = 0.f, accw = 0.f;
    if (*spillc != 0 && sl == 0) {
        s = extra0[(size_t)node * 72 + (dl >> 1)];
        float4 ea = ((const float4*)(extra0 + (size_t)node * 72 + 8))[dl];
        accx = ea.x; accy = ea.y; accz = ea.z; accw = ea.w;
    }
    for (int e = 0; e < end; e += 8) {
        uint4 kv[4];
        int idx[4];
        #pragma unroll
        for (int j = 0; j < 4; ++j) {
            idx[j] = e + 2 * j + sl;
            int c = __shfl(myadj, sbase + min(idx[j], end - 1));
            kv[j] = ((const uint4*)(KV0 + (size_t)c * 64))[dl];
        }
        #pragma unroll
        for (int j = 0; j < 4; ++j) {
            float p = q4.x * bflo(kv[j].x) + q4.y * bflo(kv[j].y)
                    + q4.z * bflo(kv[j].z) + q4.w * bflo(kv[j].w);
            p += __shfl_xor(p, 1);   // head reduce: lanes 2h,2h+1
            bool valid = (idx[j] == 0) | (idx[j] < end);
            float w = valid ? __expf(p - SM_SHIFT) : 0.f;
            s += w;
            accx += w * bfhi(kv[j].x);
            accy += w * bfhi(kv[j].y);
            accz += w * bfhi(kv[j].z);
            accw += w * bfhi(kv[j].w);
        }
    }
    s    += __shfl_xor(s, 16);
    accx += __shfl_xor(accx, 16);
    accy += __shfl_xor(accy, 16);
    accz += __shfl_xor(accz, 16);
    accw += __shfl_xor(accw, 16);
    float4 bp = ((const float4*)b0)[dl];
    float4 h;
    h.x = fmaxf(accx / s + bp.x, 0.f);
    h.y = fmaxf(accy / s + bp.y, 0.f);
    h.z = fmaxf(accz / s + bp.z, 0.f);
    h.w = fmaxf(accw / s + bp.w, 0.f);
    if (sl == 0) ((float4*)hs[half])[dl] = h;
    // --- node1 epilogue: half-wave computes 42 GEMV cols; lane l: colA=l, colB=32+l ---
    {
        int colB = 32 + l;
        const float* wA = wv1 + l;
        const float* wB = (colB < 40) ? (wv1 + colB)
                        : ((colB == 40) ? wq1 : wk1);
        int strideB = (colB < 40) ? 40 : 1;
        float accA = 0.f, accB = 0.f;
        #pragma unroll 4
        for (int k = 0; k < 64; ++k) {
            float hk = hs[half][k];
            accA += hk * wA[k * 40];
            accB += hk * wB[k * strideB];
        }
        V1u[(size_t)node * 40 + l] = f2bf(accA);
        if (colB < 40) {
            V1u[(size_t)node * 40 + colB] = f2bf(accB);
        } else if (colB == 40) {
            Q1[node] = fmaxf(accB + bq1[0], 0.f);
        } else if (colB == 41) {
            K1[node] = fmaxf(accB + bk1[0], 0.f);
        }
    }
}

// ---------------- Layer-1 fused: per-lane edge weights + shfl; 8-deep V-gather loop ----------------
__global__ __launch_bounds__(256) void k_fuse1(
    const int* __restrict__ cnt, const unsigned short* __restrict__ adj,
    const float* __restrict__ Q1, const float* __restrict__ K1,
    const unsigned int* __restrict__ V1p, const float* __restrict__ extra1,
    const int* __restrict__ spillc, const float* __restrict__ b1,
    float* __restrict__ out, int n) {
    int wid = threadIdx.x >> 6;
    int lane = threadIdx.x & 63;
    int sub = lane >> 5;
    int l = lane & 31;
    int node = blockIdx.x * 8 + wid * 2 + sub;
    if (node >= n) return;
    float qr = Q1[node];
    int end = min(cnt[node], CAP);
    int myadj = (int)adj[(size_t)node * CAP + l];
    float wl = (l < end) ? __expf(qr * K1[myadj] - SM_SHIFT) : 0.f;
    float ssum = wl;
    #pragma unroll
    for (int off = 1; off < 32; off <<= 1) ssum += __shfl_xor(ssum, off);
    bool act = (l < 20);
    float aL[4] = {0.f, 0.f, 0.f, 0.f};
    float aH[4] = {0.f, 0.f, 0.f, 0.f};
    if (*spillc != 0) {
        ssum += extra1[(size_t)node * 44];
        if (act) {
            aL[0] = extra1[(size_t)node * 44 + 4 + 2 * l];
            aH[0] = extra1[(size_t)node * 44 + 5 + 2 * l];
        }
    }
    int sbase = sub * 32;
    for (int e = 0; e < end; e += 8) {
        float ww[8];
        int cc[8];
        #pragma unroll
        for (int i = 0; i < 8; ++i) {
            ww[i] = __shfl(wl, sbase + min(e + i, 31));
            cc[i] = __shfl(myadj, sbase + min(e + i, end - 1));
        }
        unsigned int pv[8];
        #pragma unroll
        for (int i = 0; i < 8; ++i)
            pv[i] = act ? V1p[(size_t)cc[i] * 20 + l] : 0u;
        #pragma unroll
        for (int i = 0; i < 8; ++i) {
            aL[i & 3] += ww[i] * bflo(pv[i]);
            aH[i & 3] += ww[i] * bfhi(pv[i]);
        }
    }
    float aLs = (aL[0] + aL[1]) + (aL[2] + aL[3]);
    float aHs = (aH[0] + aH[1]) + (aH[2] + aH[3]);
    if (act) {
        const float2* b1p = (const float2*)b1;
        float2 bb = b1p[l];
        float2 o;
        o.x = aLs / ssum + bb.x;
        o.y = aHs / ssum + bb.y;
        ((float2*)out)[(size_t)node * 20 + l] = o;
    }
}

extern "C" void kernel_launch(void* const* d_in, const int* in_sizes, int n_in,
                              void* d_out, int out_size, void* d_ws, size_t ws_size,
                              hipStream_t stream) {
    const float* x   = (const float*)d_in[0];
    const int*   ei  = (const int*)d_in[1];
    const float* wq0 = (const float*)d_in[2];
    const float* bq0 = (const float*)d_in[3];
    const float* wk0 = (const float*)d_in[4];
    const float* bk0 = (const float*)d_in[5];
    const float* wv0 = (const float*)d_in[6];
    const float* b0  = (const float*)d_in[7];
    const float* wq1 = (const float*)d_in[8];
    const float* bq1 = (const float*)d_in[9];
    const float* wk1 = (const float*)d_in[10];
    const float* bk1 = (const float*)d_in[11];
    const float* wv1 = (const float*)d_in[12];
    const float* b1  = (const float*)d_in[13];
    float* out = (float*)d_out;

    int n    = in_sizes[0] / Fdim;   // 50000
    int E_   = in_sizes[1] / 2;      // 800000
    int Etot = E_ + n;               // + self-loops
    const int* row = ei;
    const int* col = ei + E_;

    float* ws = (float*)d_ws;
    float*          Q0     = ws;                   ws += (size_t)n * 64;
    unsigned int*   KV0    = (unsigned int*)ws;    ws += (size_t)n * 64;
    unsigned short* V1u    = (unsigned short*)ws;  ws += (size_t)n * 20;
    float*          Q1     = ws;                   ws += n;
    float*          K1     = ws;                   ws += n;
    unsigned short* adj    = (unsigned short*)ws;  ws += (size_t)n * (CAP / 2);
    unsigned short* WT     = (unsigned short*)ws;  ws += (192 * Fdim) / 2;
    // ---- small zero region (memset) ----
    int*            cnt    = (int*)ws;             ws += n;
    int*            spillc = (int*)ws;             ws += 4;
    // ---- large zero region (zeroed inside k_node0adj scatter blocks) ----
    float*          extra0 = ws;                   ws += (size_t)n * 72;
    float*          extra1 = ws;                   ws += (size_t)n * 44;
    unsigned int*   spill  = (unsigned int*)ws;

    int extra_zero_q = (int)(((size_t)n * 72 + (size_t)n * 44) / 4);
    int ngemm = (n + 63) / 64;   // 782 GEMM blocks
    int ngrid0 = 2048;           // + 1266 scatter/zero blocks

    // --- prep: zero cnt+spillc only; transpose+bf16 weights ---
    hipMemsetAsync(cnt, 0, ((size_t)n + 4) * sizeof(int), stream);
    k_wt<<<(192 * Fdim + 255) / 256, 256, 0, stream>>>(wq0, wk0, wv0, WT);

    // --- role-split: GEMM blocks || scatter+zero blocks, co-scheduled ---
    k_node0adj<<<ngrid0, 256, 0, stream>>>(x, WT, bq0, bk0, Q0, KV0,
                                           row, col, cnt, adj,
                                           spill, spillc,
                                           (float4*)extra0, extra_zero_q,
                                           E_, Etot, n, ngemm);
    k_spill0<<<64, 256, 0, stream>>>(spillc, spill, Q0, KV0, extra0);

    // --- Layer 0 fused (+ layer-1 node transform epilogue) ---
    k_fuse0<<<(n + 7) / 8, 256, 0, stream>>>(cnt, adj, Q0, KV0, extra0, spillc, b0,
                                             wq1, bq1, wk1, bk1, wv1,
                                             Q1, K1, V1u, n);
    k_spill1<<<64, 256, 0, stream>>>(spillc, spill, Q1, K1, V1u, extra1);

    // --- Layer 1 fused ---
    k_fuse1<<<(n + 7) / 8, 256, 0, stream>>>(cnt, adj, Q1, K1,
                                             (const unsigned int*)V1u, extra1,
                                             spillc, b1, out, n);
}

// Round 25
// 169.879 us; speedup vs baseline: 1.0325x; 1.0325x over previous
//
#include <hip/hip_runtime.h>
#include <hip/hip_bf16.h>
#include <math.h>

#define Fdim 128
#define CAP 32
// Fixed softmax shift: p >= 0 always (relu'd Q,K); p <= ~70 worst case.
#define SM_SHIFT 20.0f

typedef __attribute__((ext_vector_type(8))) short bf16x8;
typedef __attribute__((ext_vector_type(4))) float f32x4;

__device__ __forceinline__ unsigned short f2bf(float x) {
    __hip_bfloat16 h = __float2bfloat16(x);
    return *(unsigned short*)&h;
}
__device__ __forceinline__ unsigned int pk2bf(float a, float b) {
    return (unsigned int)f2bf(a) | ((unsigned int)f2bf(b) << 16);
}
__device__ __forceinline__ float bflo(unsigned int u) {
    unsigned int b = u << 16;
    return *(float*)&b;
}
__device__ __forceinline__ float bfhi(unsigned int u) {
    unsigned int b = u & 0xffff0000u;
    return *(float*)&b;
}

// ---------------- Weight prep: WT[c][k] bf16, c in [0,192) = q|k|v cols ----------------
__global__ void k_wt(const float* __restrict__ wq, const float* __restrict__ wk,
                     const float* __restrict__ wv, unsigned short* __restrict__ WT) {
    int t = blockIdx.x * blockDim.x + threadIdx.x;
    if (t >= 192 * Fdim) return;
    int c = t >> 7, k = t & 127;
    float v = (c < 64) ? wq[k * 64 + c]
            : (c < 128) ? wk[k * 64 + (c - 64)]
                        : wv[k * 64 + (c - 128)];
    WT[t] = f2bf(v);
}

// ---------------- Lazy extra-zeroing: runs only if spills exist ----------------
__global__ void k_zeroex(const int* __restrict__ spillc,
                         float4* __restrict__ extra_zero, int extra_zero_q) {
    if (*spillc == 0) return;   // common case: immediate exit
    int stride = gridDim.x * blockDim.x;
    float4 z = make_float4(0.f, 0.f, 0.f, 0.f);
    for (int i = blockIdx.x * blockDim.x + threadIdx.x; i < extra_zero_q; i += stride)
        extra_zero[i] = z;
}

// ---------------- MFMA node-0 transform + XCD-partitioned adjacency build ----------------
// Grid OVERSIZED (2048 blocks): ALL blocks scatter (partition p = bid&7 owns
// rows with ((r>>4)&7)==p -> single-XCD adj/cnt lines); first 782 also GEMM.
__global__ __launch_bounds__(256) void k_node0adj(
    const float* __restrict__ x,
    const unsigned short* __restrict__ WT,
    const float* __restrict__ bq, const float* __restrict__ bk,
    float* __restrict__ Q0, unsigned int* __restrict__ KV0,
    const int* __restrict__ row, const int* __restrict__ col,
    int* __restrict__ cnt, unsigned short* __restrict__ adj,
    unsigned int* __restrict__ spill, int* __restrict__ spill_cnt,
    int E_, int Etot, int n) {
    int t = threadIdx.x;
    // --- adjacency slice: quarter-streams, partition-filtered ---
    {
        int p = blockIdx.x & 7;
        int gb = blockIdx.x >> 3;
        int ngb = gridDim.x >> 3;
        if (gb < ngb) {
            int quarter = (Etot + 3) >> 2;
            int stride = ngb * 256;
            for (int base = gb * 256 + t; base < quarter; base += stride) {
                #pragma unroll
                for (int qd = 0; qd < 4; ++qd) {
                    int e = base + qd * quarter;
                    if (e < Etot) {
                        int r, c;
                        if (e < E_) { r = row[e]; c = col[e]; } else { r = e - E_; c = r; }
                        if (((r >> 4) & 7) == p) {
                            int pos = atomicAdd(&cnt[r], 1);
                            if (pos < CAP) {
                                adj[(size_t)r * CAP + pos] = (unsigned short)c;
                            } else {
                                int sp = atomicAdd(spill_cnt, 1);
                                spill[sp] = ((unsigned int)r << 16) | (unsigned int)c;
                            }
                        }
                    }
                }
            }
        }
    }
    // --- MFMA GEMM: rows = nodes, cols 0-63 Q, 64-127 K, 128-191 V ---
    int wv_ = t >> 6;
    int ln = t & 63;
    int rowbase = blockIdx.x * 64 + wv_ * 16;
    if (rowbase >= n) return;   // oversized-grid blocks exit here
    int cl = ln & 15;
    int kgrp = (ln >> 4) * 8;
    int arow = rowbase + cl;
    int arowc = min(arow, n - 1);
    f32x4 acc[12];
    #pragma unroll
    for (int i = 0; i < 12; ++i) acc[i] = (f32x4)(0.f);
    #pragma unroll
    for (int ks = 0; ks < 4; ++ks) {
        int k0 = ks * 32 + kgrp;
        const float4* xp = (const float4*)(x + (size_t)arowc * Fdim + k0);
        float4 xa = xp[0], xb = xp[1];
        union { unsigned int u[4]; bf16x8 v; } af;
        af.u[0] = pk2bf(xa.x, xa.y);
        af.u[1] = pk2bf(xa.z, xa.w);
        af.u[2] = pk2bf(xb.x, xb.y);
        af.u[3] = pk2bf(xb.z, xb.w);
        #pragma unroll
        for (int tt = 0; tt < 12; ++tt) {
            bf16x8 bf = *(const bf16x8*)(WT + (size_t)(tt * 16 + cl) * Fdim + k0);
            acc[tt] = __builtin_amdgcn_mfma_f32_16x16x32_bf16(af.v, bf, acc[tt], 0, 0, 0);
        }
    }
    int rgrp = (ln >> 4) * 4;
    #pragma unroll
    for (int r = 0; r < 4; ++r) {
        int node = rowbase + rgrp + r;
        if (node < n) {
            #pragma unroll
            for (int tq = 0; tq < 4; ++tq) {
                float q = fmaxf(acc[tq][r] + bq[tq * 16 + cl], 0.f);
                Q0[(size_t)node * 64 + tq * 16 + cl] = q;
            }
            #pragma unroll
            for (int tk = 0; tk < 4; ++tk) {
                float kk = fmaxf(acc[4 + tk][r] + bk[tk * 16 + cl], 0.f);
                float vv = acc[8 + tk][r];
                KV0[(size_t)node * 64 + tk * 16 + cl] =
                    (unsigned int)f2bf(kk) | ((unsigned int)f2bf(vv) << 16);
            }
        }
    }
}

// ---------------- Spill fixup, layer 0: one wave per spilled edge ----------------
__global__ void k_spill0(const int* __restrict__ spill_cnt,
                         const unsigned int* __restrict__ spill,
                         const float* __restrict__ Q0,
                         const unsigned int* __restrict__ KV0,
                         float* __restrict__ extra0) {
    int sc = *spill_cnt;
    int widx = (blockIdx.x * blockDim.x + threadIdx.x) >> 6;
    int nw = (gridDim.x * blockDim.x) >> 6;
    int j = threadIdx.x & 63;
    for (int i = widx; i < sc; i += nw) {
        unsigned int pc = spill[i];
        int r = pc >> 16, c = pc & 0xFFFF;
        float q = Q0[(size_t)r * 64 + j] * 0.35355339059327373f;
        unsigned int kv = KV0[(size_t)c * 64 + j];
        float p = q * bflo(kv);
        #pragma unroll
        for (int off = 1; off < 8; off <<= 1) p += __shfl_xor(p, off);
        float w = __expf(p - SM_SHIFT);
        atomicAdd(&extra0[(size_t)r * 72 + 8 + j], w * bfhi(kv));
        if ((j & 7) == 0) atomicAdd(&extra0[(size_t)r * 72 + (j >> 3)], w);
    }
}

// ---------------- Spill fixup, layer 1 ----------------
__global__ void k_spill1(const int* __restrict__ spill_cnt,
                         const unsigned int* __restrict__ spill,
                         const float* __restrict__ Q1, const float* __restrict__ K1,
                         const unsigned short* __restrict__ V1u,
                         float* __restrict__ extra1) {
    int sc = *spill_cnt;
    int widx = (blockIdx.x * blockDim.x + threadIdx.x) >> 6;
    int nw = (gridDim.x * blockDim.x) >> 6;
    int j = threadIdx.x & 63;
    for (int i = widx; i < sc; i += nw) {
        unsigned int pc = spill[i];
        int r = pc >> 16, c = pc & 0xFFFF;
        float w = __expf(Q1[r] * K1[c] - SM_SHIFT);
        if (j < 40) {
            float v = bflo((unsigned int)V1u[(size_t)c * 40 + j]);
            atomicAdd(&extra1[(size_t)r * 44 + 4 + j], w * v);
        } else if (j == 63) {
            atomicAdd(&extra1[(size_t)r * 44], w);
        }
    }
}

// ---------------- Layer-0 fused: 16-lanes-per-edge uint4 gathers ----------------
__global__ __launch_bounds__(256) void k_fuse0(
    const int* __restrict__ cnt, const unsigned short* __restrict__ adj,
    const float* __restrict__ Q0, const unsigned int* __restrict__ KV0,
    const float* __restrict__ extra0, const int* __restrict__ spillc,
    const float* __restrict__ b0,
    const float* __restrict__ wq1, const float* __restrict__ bq1,
    const float* __restrict__ wk1, const float* __restrict__ bk1,
    const float* __restrict__ wv1,
    float* __restrict__ Q1, float* __restrict__ K1,
    unsigned short* __restrict__ V1u, int n) {
    __shared__ float hs[8][64];
    int wid = threadIdx.x >> 6;
    int lane = threadIdx.x & 63;
    int sub = lane >> 5;
    int l = lane & 31;
    int sl = l >> 4;           // edge slot within half
    int dl = l & 15;           // dim-lane: dims 4dl..4dl+3
    int half = wid * 2 + sub;
    int node = blockIdx.x * 8 + half;
    if (node >= n) return;
    const float SC = 0.35355339059327373f;
    float4 q4 = ((const float4*)(Q0 + (size_t)node * 64))[dl];
    q4.x *= SC; q4.y *= SC; q4.z *= SC; q4.w *= SC;
    int end = min(cnt[node], CAP);
    int myadj = (int)adj[(size_t)node * CAP + l];
    int sbase = sub * 32;
    float s = 0.f;
    float accx = 0.f, accy = 0.f, accz = 0.f, accw = 0.f;
    if (*spillc != 0 && sl == 0) {
        s = extra0[(size_t)node * 72 + (dl >> 1)];
        float4 ea = ((const float4*)(extra0 + (size_t)node * 72 + 8))[dl];
        accx = ea.x; accy = ea.y; accz = ea.z; accw = ea.w;
    }
    for (int e = 0; e < end; e += 8) {
        uint4 kv[4];
        int idx[4];
        #pragma unroll
        for (int j = 0; j < 4; ++j) {
            idx[j] = e + 2 * j + sl;
            int c = __shfl(myadj, sbase + min(idx[j], end - 1));
            kv[j] = ((const uint4*)(KV0 + (size_t)c * 64))[dl];
        }
        #pragma unroll
        for (int j = 0; j < 4; ++j) {
            float p = q4.x * bflo(kv[j].x) + q4.y * bflo(kv[j].y)
                    + q4.z * bflo(kv[j].z) + q4.w * bflo(kv[j].w);
            p += __shfl_xor(p, 1);   // head reduce: lanes 2h,2h+1
            bool valid = (idx[j] == 0) | (idx[j] < end);
            float w = valid ? __expf(p - SM_SHIFT) : 0.f;
            s += w;
            accx += w * bfhi(kv[j].x);
            accy += w * bfhi(kv[j].y);
            accz += w * bfhi(kv[j].z);
            accw += w * bfhi(kv[j].w);
        }
    }
    s    += __shfl_xor(s, 16);
    accx += __shfl_xor(accx, 16);
    accy += __shfl_xor(accy, 16);
    accz += __shfl_xor(accz, 16);
    accw += __shfl_xor(accw, 16);
    float4 bp = ((const float4*)b0)[dl];
    float4 h;
    h.x = fmaxf(accx / s + bp.x, 0.f);
    h.y = fmaxf(accy / s + bp.y, 0.f);
    h.z = fmaxf(accz / s + bp.z, 0.f);
    h.w = fmaxf(accw / s + bp.w, 0.f);
    if (sl == 0) ((float4*)hs[half])[dl] = h;
    // --- node1 epilogue: half-wave computes 42 GEMV cols; lane l: colA=l, colB=32+l ---
    {
        int colB = 32 + l;
        const float* wA = wv1 + l;
        const float* wB = (colB < 40) ? (wv1 + colB)
                        : ((colB == 40) ? wq1 : wk1);
        int strideB = (colB < 40) ? 40 : 1;
        float accA = 0.f, accB = 0.f;
        #pragma unroll 4
        for (int k = 0; k < 64; ++k) {
            float hk = hs[half][k];
            accA += hk * wA[k * 40];
            accB += hk * wB[k * strideB];
        }
        V1u[(size_t)node * 40 + l] = f2bf(accA);
        if (colB < 40) {
            V1u[(size_t)node * 40 + colB] = f2bf(accB);
        } else if (colB == 40) {
            Q1[node] = fmaxf(accB + bq1[0], 0.f);
        } else if (colB == 41) {
            K1[node] = fmaxf(accB + bk1[0], 0.f);
        }
    }
}

// ---------------- Layer-1 fused: per-lane edge weights + shfl; 8-deep V-gather loop ----------------
__global__ __launch_bounds__(256) void k_fuse1(
    const int* __restrict__ cnt, const unsigned short* __restrict__ adj,
    const float* __restrict__ Q1, const float* __restrict__ K1,
    const unsigned int* __restrict__ V1p, const float* __restrict__ extra1,
    const int* __restrict__ spillc, const float* __restrict__ b1,
    float* __restrict__ out, int n) {
    int wid = threadIdx.x >> 6;
    int lane = threadIdx.x & 63;
    int sub = lane >> 5;
    int l = lane & 31;
    int node = blockIdx.x * 8 + wid * 2 + sub;
    if (node >= n) return;
    float qr = Q1[node];
    int end = min(cnt[node], CAP);
    int myadj = (int)adj[(size_t)node * CAP + l];
    float wl = (l < end) ? __expf(qr * K1[myadj] - SM_SHIFT) : 0.f;
    float ssum = wl;
    #pragma unroll
    for (int off = 1; off < 32; off <<= 1) ssum += __shfl_xor(ssum, off);
    bool act = (l < 20);
    float aL[4] = {0.f, 0.f, 0.f, 0.f};
    float aH[4] = {0.f, 0.f, 0.f, 0.f};
    if (*spillc != 0) {
        ssum += extra1[(size_t)node * 44];
        if (act) {
            aL[0] = extra1[(size_t)node * 44 + 4 + 2 * l];
            aH[0] = extra1[(size_t)node * 44 + 5 + 2 * l];
        }
    }
    int sbase = sub * 32;
    for (int e = 0; e < end; e += 8) {
        float ww[8];
        int cc[8];
        #pragma unroll
        for (int i = 0; i < 8; ++i) {
            ww[i] = __shfl(wl, sbase + min(e + i, 31));
            cc[i] = __shfl(myadj, sbase + min(e + i, end - 1));
        }
        unsigned int pv[8];
        #pragma unroll
        for (int i = 0; i < 8; ++i)
            pv[i] = act ? V1p[(size_t)cc[i] * 20 + l] : 0u;
        #pragma unroll
        for (int i = 0; i < 8; ++i) {
            aL[i & 3] += ww[i] * bflo(pv[i]);
            aH[i & 3] += ww[i] * bfhi(pv[i]);
        }
    }
    float aLs = (aL[0] + aL[1]) + (aL[2] + aL[3]);
    float aHs = (aH[0] + aH[1]) + (aH[2] + aH[3]);
    if (act) {
        const float2* b1p = (const float2*)b1;
        float2 bb = b1p[l];
        float2 o;
        o.x = aLs / ssum + bb.x;
        o.y = aHs / ssum + bb.y;
        ((float2*)out)[(size_t)node * 20 + l] = o;
    }
}

extern "C" void kernel_launch(void* const* d_in, const int* in_sizes, int n_in,
                              void* d_out, int out_size, void* d_ws, size_t ws_size,
                              hipStream_t stream) {
    const float* x   = (const float*)d_in[0];
    const int*   ei  = (const int*)d_in[1];
    const float* wq0 = (const float*)d_in[2];
    const float* bq0 = (const float*)d_in[3];
    const float* wk0 = (const float*)d_in[4];
    const float* bk0 = (const float*)d_in[5];
    const float* wv0 = (const float*)d_in[6];
    const float* b0  = (const float*)d_in[7];
    const float* wq1 = (const float*)d_in[8];
    const float* bq1 = (const float*)d_in[9];
    const float* wk1 = (const float*)d_in[10];
    const float* bk1 = (const float*)d_in[11];
    const float* wv1 = (const float*)d_in[12];
    const float* b1  = (const float*)d_in[13];
    float* out = (float*)d_out;

    int n    = in_sizes[0] / Fdim;   // 50000
    int E_   = in_sizes[1] / 2;      // 800000
    int Etot = E_ + n;               // + self-loops
    const int* row = ei;
    const int* col = ei + E_;

    float* ws = (float*)d_ws;
    float*          Q0     = ws;                   ws += (size_t)n * 64;
    unsigned int*   KV0    = (unsigned int*)ws;    ws += (size_t)n * 64;
    unsigned short* V1u    = (unsigned short*)ws;  ws += (size_t)n * 20;
    float*          Q1     = ws;                   ws += n;
    float*          K1     = ws;                   ws += n;
    unsigned short* adj    = (unsigned short*)ws;  ws += (size_t)n * (CAP / 2);
    unsigned short* WT     = (unsigned short*)ws;  ws += (192 * Fdim) / 2;
    // ---- small zero region (memset) ----
    int*            cnt    = (int*)ws;             ws += n;
    int*            spillc = (int*)ws;             ws += 4;
    // ---- extra region: zeroed lazily by k_zeroex only when spills exist ----
    float*          extra0 = ws;                   ws += (size_t)n * 72;
    float*          extra1 = ws;                   ws += (size_t)n * 44;
    unsigned int*   spill  = (unsigned int*)ws;

    int extra_zero_q = (int)(((size_t)n * 72 + (size_t)n * 44) / 4);
    int ngrid0 = 2048;   // all blocks scatter; first 782 also GEMM

    // --- prep: zero cnt+spillc only; transpose+bf16 weights ---
    hipMemsetAsync(cnt, 0, ((size_t)n + 4) * sizeof(int), stream);
    k_wt<<<(192 * Fdim + 255) / 256, 256, 0, stream>>>(wq0, wk0, wv0, WT);

    // --- MFMA node0 GEMM + adjacency build (no zero-slice: no L2 pollution) ---
    k_node0adj<<<ngrid0, 256, 0, stream>>>(x, WT, bq0, bk0, Q0, KV0,
                                           row, col, cnt, adj,
                                           spill, spillc, E_, Etot, n);
    // --- lazy zero of extra region (early-exits when no spills) ---
    k_zeroex<<<512, 256, 0, stream>>>(spillc, (float4*)extra0, extra_zero_q);
    k_spill0<<<64, 256, 0, stream>>>(spillc, spill, Q0, KV0, extra0);

    // --- Layer 0 fused (+ layer-1 node transform epilogue) ---
    k_fuse0<<<(n + 7) / 8, 256, 0, stream>>>(cnt, adj, Q0, KV0, extra0, spillc, b0,
                                             wq1, bq1, wk1, bk1, wv1,
                                             Q1, K1, V1u, n);
    k_spill1<<<64, 256, 0, stream>>>(spillc, spill, Q1, K1, V1u, extra1);

    // --- Layer 1 fused ---
    k_fuse1<<<(n + 7) / 8, 256, 0, stream>>>(cnt, adj, Q1, K1,
                                             (const unsigned int*)V1u, extra1,
                                             spillc, b1, out, n);
}

// Round 26
// 166.713 us; speedup vs baseline: 1.0521x; 1.0190x over previous
//
#include <hip/hip_runtime.h>
#include <hip/hip_bf16.h>
#include <math.h>

#define Fdim 128
#define CAP 32
// Fixed softmax shift: p >= 0 always (relu'd Q,K); p <= ~70 worst case.
#define SM_SHIFT 20.0f

typedef __attribute__((ext_vector_type(8))) short bf16x8;
typedef __attribute__((ext_vector_type(4))) float f32x4;

__device__ __forceinline__ unsigned short f2bf(float x) {
    __hip_bfloat16 h = __float2bfloat16(x);
    return *(unsigned short*)&h;
}
__device__ __forceinline__ unsigned int pk2bf(float a, float b) {
    return (unsigned int)f2bf(a) | ((unsigned int)f2bf(b) << 16);
}
__device__ __forceinline__ float bflo(unsigned int u) {
    unsigned int b = u << 16;
    return *(float*)&b;
}
__device__ __forceinline__ float bfhi(unsigned int u) {
    unsigned int b = u & 0xffff0000u;
    return *(float*)&b;
}

// ---------------- Weight prep: WT[c][k] bf16, c in [0,192) = q|k|v cols ----------------
__global__ void k_wt(const float* __restrict__ wq, const float* __restrict__ wk,
                     const float* __restrict__ wv, unsigned short* __restrict__ WT) {
    int t = blockIdx.x * blockDim.x + threadIdx.x;
    if (t >= 192 * Fdim) return;
    int c = t >> 7, k = t & 127;
    float v = (c < 64) ? wq[k * 64 + c]
            : (c < 128) ? wk[k * 64 + (c - 64)]
                        : wv[k * 64 + (c - 128)];
    WT[t] = f2bf(v);
}

// ---------------- MFMA node-0 transform + adjacency build + extra-zeroing ----------------
// Grid OVERSIZED (2048 blocks). Order per block: scatter (latency-critical,
// clean L2) -> zero-slice (streaming) -> GEMM (first 782 blocks only).
__global__ __launch_bounds__(256) void k_node0adj(
    const float* __restrict__ x,
    const unsigned short* __restrict__ WT,
    const float* __restrict__ bq, const float* __restrict__ bk,
    float* __restrict__ Q0, unsigned int* __restrict__ KV0,
    const int* __restrict__ row, const int* __restrict__ col,
    int* __restrict__ cnt, unsigned short* __restrict__ adj,
    unsigned int* __restrict__ spill, int* __restrict__ spill_cnt,
    float4* __restrict__ extra_zero, int extra_zero_q,
    int E_, int Etot, int n) {
    int t = threadIdx.x;
    // --- adjacency slice FIRST: quarter-streams, partition-filtered ---
    {
        int p = blockIdx.x & 7;
        int gb = blockIdx.x >> 3;
        int ngb = gridDim.x >> 3;
        if (gb < ngb) {
            int quarter = (Etot + 3) >> 2;
            int stride = ngb * 256;
            for (int base = gb * 256 + t; base < quarter; base += stride) {
                #pragma unroll
                for (int qd = 0; qd < 4; ++qd) {
                    int e = base + qd * quarter;
                    if (e < Etot) {
                        int r, c;
                        if (e < E_) { r = row[e]; c = col[e]; } else { r = e - E_; c = r; }
                        if (((r >> 4) & 7) == p) {
                            int pos = atomicAdd(&cnt[r], 1);
                            if (pos < CAP) {
                                adj[(size_t)r * CAP + pos] = (unsigned short)c;
                            } else {
                                int sp = atomicAdd(spill_cnt, 1);
                                spill[sp] = ((unsigned int)r << 16) | (unsigned int)c;
                            }
                        }
                    }
                }
            }
        }
    }
    // --- zero the spill-extra region (after scatter: no mid-scatter L2 pollution) ---
    {
        int stride = gridDim.x * 256;
        float4 z = make_float4(0.f, 0.f, 0.f, 0.f);
        for (int i = blockIdx.x * 256 + t; i < extra_zero_q; i += stride)
            extra_zero[i] = z;
    }
    // --- MFMA GEMM: rows = nodes, cols 0-63 Q, 64-127 K, 128-191 V ---
    int wv_ = t >> 6;
    int ln = t & 63;
    int rowbase = blockIdx.x * 64 + wv_ * 16;
    if (rowbase >= n) return;   // oversized-grid blocks exit here
    int cl = ln & 15;
    int kgrp = (ln >> 4) * 8;
    int arow = rowbase + cl;
    int arowc = min(arow, n - 1);
    f32x4 acc[12];
    #pragma unroll
    for (int i = 0; i < 12; ++i) acc[i] = (f32x4)(0.f);
    #pragma unroll
    for (int ks = 0; ks < 4; ++ks) {
        int k0 = ks * 32 + kgrp;
        const float4* xp = (const float4*)(x + (size_t)arowc * Fdim + k0);
        float4 xa = xp[0], xb = xp[1];
        union { unsigned int u[4]; bf16x8 v; } af;
        af.u[0] = pk2bf(xa.x, xa.y);
        af.u[1] = pk2bf(xa.z, xa.w);
        af.u[2] = pk2bf(xb.x, xb.y);
        af.u[3] = pk2bf(xb.z, xb.w);
        #pragma unroll
        for (int tt = 0; tt < 12; ++tt) {
            bf16x8 bf = *(const bf16x8*)(WT + (size_t)(tt * 16 + cl) * Fdim + k0);
            acc[tt] = __builtin_amdgcn_mfma_f32_16x16x32_bf16(af.v, bf, acc[tt], 0, 0, 0);
        }
    }
    int rgrp = (ln >> 4) * 4;
    #pragma unroll
    for (int r = 0; r < 4; ++r) {
        int node = rowbase + rgrp + r;
        if (node < n) {
            #pragma unroll
            for (int tq = 0; tq < 4; ++tq) {
                float q = fmaxf(acc[tq][r] + bq[tq * 16 + cl], 0.f);
                Q0[(size_t)node * 64 + tq * 16 + cl] = q;
            }
            #pragma unroll
            for (int tk = 0; tk < 4; ++tk) {
                float kk = fmaxf(acc[4 + tk][r] + bk[tk * 16 + cl], 0.f);
                float vv = acc[8 + tk][r];
                KV0[(size_t)node * 64 + tk * 16 + cl] =
                    (unsigned int)f2bf(kk) | ((unsigned int)f2bf(vv) << 16);
            }
        }
    }
}

// ---------------- Spill fixup, layer 0: one wave per spilled edge ----------------
__global__ void k_spill0(const int* __restrict__ spill_cnt,
                         const unsigned int* __restrict__ spill,
                         const float* __restrict__ Q0,
                         const unsigned int* __restrict__ KV0,
                         float* __restrict__ extra0) {
    int sc = *spill_cnt;
    int widx = (blockIdx.x * blockDim.x + threadIdx.x) >> 6;
    int nw = (gridDim.x * blockDim.x) >> 6;
    int j = threadIdx.x & 63;
    for (int i = widx; i < sc; i += nw) {
        unsigned int pc = spill[i];
        int r = pc >> 16, c = pc & 0xFFFF;
        float q = Q0[(size_t)r * 64 + j] * 0.35355339059327373f;
        unsigned int kv = KV0[(size_t)c * 64 + j];
        float p = q * bflo(kv);
        #pragma unroll
        for (int off = 1; off < 8; off <<= 1) p += __shfl_xor(p, off);
        float w = __expf(p - SM_SHIFT);
        atomicAdd(&extra0[(size_t)r * 72 + 8 + j], w * bfhi(kv));
        if ((j & 7) == 0) atomicAdd(&extra0[(size_t)r * 72 + (j >> 3)], w);
    }
}

// ---------------- Spill fixup, layer 1 ----------------
__global__ void k_spill1(const int* __restrict__ spill_cnt,
                         const unsigned int* __restrict__ spill,
                         const float* __restrict__ Q1, const float* __restrict__ K1,
                         const unsigned short* __restrict__ V1u,
                         float* __restrict__ extra1) {
    int sc = *spill_cnt;
    int widx = (blockIdx.x * blockDim.x + threadIdx.x) >> 6;
    int nw = (gridDim.x * blockDim.x) >> 6;
    int j = threadIdx.x & 63;
    for (int i = widx; i < sc; i += nw) {
        unsigned int pc = spill[i];
        int r = pc >> 16, c = pc & 0xFFFF;
        float w = __expf(Q1[r] * K1[c] - SM_SHIFT);
        if (j < 40) {
            float v = bflo((unsigned int)V1u[(size_t)c * 40 + j]);
            atomicAdd(&extra1[(size_t)r * 44 + 4 + j], w * v);
        } else if (j == 63) {
            atomicAdd(&extra1[(size_t)r * 44], w);
        }
    }
}

// ---------------- Layer-0 fused: 16-lanes-per-edge uint4 gathers ----------------
__global__ __launch_bounds__(256) void k_fuse0(
    const int* __restrict__ cnt, const unsigned short* __restrict__ adj,
    const float* __restrict__ Q0, const unsigned int* __restrict__ KV0,
    const float* __restrict__ extra0, const int* __restrict__ spillc,
    const float* __restrict__ b0,
    const float* __restrict__ wq1, const float* __restrict__ bq1,
    const float* __restrict__ wk1, const float* __restrict__ bk1,
    const float* __restrict__ wv1,
    float* __restrict__ Q1, float* __restrict__ K1,
    unsigned short* __restrict__ V1u, int n) {
    __shared__ float hs[8][64];
    int wid = threadIdx.x >> 6;
    int lane = threadIdx.x & 63;
    int sub = lane >> 5;
    int l = lane & 31;
    int sl = l >> 4;           // edge slot within half
    int dl = l & 15;           // dim-lane: dims 4dl..4dl+3
    int half = wid * 2 + sub;
    int node = blockIdx.x * 8 + half;
    if (node >= n) return;
    const float SC = 0.35355339059327373f;
    float4 q4 = ((const float4*)(Q0 + (size_t)node * 64))[dl];
    q4.x *= SC; q4.y *= SC; q4.z *= SC; q4.w *= SC;
    int end = min(cnt[node], CAP);
    int myadj = (int)adj[(size_t)node * CAP + l];
    int sbase = sub * 32;
    float s = 0.f;
    float accx = 0.f, accy = 0.f, accz = 0.f, accw = 0.f;
    if (*spillc != 0 && sl == 0) {
        s = extra0[(size_t)node * 72 + (dl >> 1)];
        float4 ea = ((const float4*)(extra0 + (size_t)node * 72 + 8))[dl];
        accx = ea.x; accy = ea.y; accz = ea.z; accw = ea.w;
    }
    for (int e = 0; e < end; e += 8) {
        uint4 kv[4];
        int idx[4];
        #pragma unroll
        for (int j = 0; j < 4; ++j) {
            idx[j] = e + 2 * j + sl;
            int c = __shfl(myadj, sbase + min(idx[j], end - 1));
            kv[j] = ((const uint4*)(KV0 + (size_t)c * 64))[dl];
        }
        #pragma unroll
        for (int j = 0; j < 4; ++j) {
            float p = q4.x * bflo(kv[j].x) + q4.y * bflo(kv[j].y)
                    + q4.z * bflo(kv[j].z) + q4.w * bflo(kv[j].w);
            p += __shfl_xor(p, 1);   // head reduce: lanes 2h,2h+1
            bool valid = (idx[j] == 0) | (idx[j] < end);
            float w = valid ? __expf(p - SM_SHIFT) : 0.f;
            s += w;
            accx += w * bfhi(kv[j].x);
            accy += w * bfhi(kv[j].y);
            accz += w * bfhi(kv[j].z);
            accw += w * bfhi(kv[j].w);
        }
    }
    s    += __shfl_xor(s, 16);
    accx += __shfl_xor(accx, 16);
    accy += __shfl_xor(accy, 16);
    accz += __shfl_xor(accz, 16);
    accw += __shfl_xor(accw, 16);
    float4 bp = ((const float4*)b0)[dl];
    float4 h;
    h.x = fmaxf(accx / s + bp.x, 0.f);
    h.y = fmaxf(accy / s + bp.y, 0.f);
    h.z = fmaxf(accz / s + bp.z, 0.f);
    h.w = fmaxf(accw / s + bp.w, 0.f);
    if (sl == 0) ((float4*)hs[half])[dl] = h;
    // --- node1 epilogue: half-wave computes 42 GEMV cols; lane l: colA=l, colB=32+l ---
    {
        int colB = 32 + l;
        const float* wA = wv1 + l;
        const float* wB = (colB < 40) ? (wv1 + colB)
                        : ((colB == 40) ? wq1 : wk1);
        int strideB = (colB < 40) ? 40 : 1;
        float accA = 0.f, accB = 0.f;
        #pragma unroll 4
        for (int k = 0; k < 64; ++k) {
            float hk = hs[half][k];
            accA += hk * wA[k * 40];
            accB += hk * wB[k * strideB];
        }
        V1u[(size_t)node * 40 + l] = f2bf(accA);
        if (colB < 40) {
            V1u[(size_t)node * 40 + colB] = f2bf(accB);
        } else if (colB == 40) {
            Q1[node] = fmaxf(accB + bq1[0], 0.f);
        } else if (colB == 41) {
            K1[node] = fmaxf(accB + bk1[0], 0.f);
        }
    }
}

// ---------------- Layer-1 fused: per-lane edge weights + shfl; 8-deep V-gather loop ----------------
__global__ __launch_bounds__(256) void k_fuse1(
    const int* __restrict__ cnt, const unsigned short* __restrict__ adj,
    const float* __restrict__ Q1, const float* __restrict__ K1,
    const unsigned int* __restrict__ V1p, const float* __restrict__ extra1,
    const int* __restrict__ spillc, const float* __restrict__ b1,
    float* __restrict__ out, int n) {
    int wid = threadIdx.x >> 6;
    int lane = threadIdx.x & 63;
    int sub = lane >> 5;
    int l = lane & 31;
    int node = blockIdx.x * 8 + wid * 2 + sub;
    if (node >= n) return;
    float qr = Q1[node];
    int end = min(cnt[node], CAP);
    int myadj = (int)adj[(size_t)node * CAP + l];
    float wl = (l < end) ? __expf(qr * K1[myadj] - SM_SHIFT) : 0.f;
    float ssum = wl;
    #pragma unroll
    for (int off = 1; off < 32; off <<= 1) ssum += __shfl_xor(ssum, off);
    bool act = (l < 20);
    float aL[4] = {0.f, 0.f, 0.f, 0.f};
    float aH[4] = {0.f, 0.f, 0.f, 0.f};
    if (*spillc != 0) {
        ssum += extra1[(size_t)node * 44];
        if (act) {
            aL[0] = extra1[(size_t)node * 44 + 4 + 2 * l];
            aH[0] = extra1[(size_t)node * 44 + 5 + 2 * l];
        }
    }
    int sbase = sub * 32;
    for (int e = 0; e < end; e += 8) {
        float ww[8];
        int cc[8];
        #pragma unroll
        for (int i = 0; i < 8; ++i) {
            ww[i] = __shfl(wl, sbase + min(e + i, 31));
            cc[i] = __shfl(myadj, sbase + min(e + i, end - 1));
        }
        unsigned int pv[8];
        #pragma unroll
        for (int i = 0; i < 8; ++i)
            pv[i] = act ? V1p[(size_t)cc[i] * 20 + l] : 0u;
        #pragma unroll
        for (int i = 0; i < 8; ++i) {
            aL[i & 3] += ww[i] * bflo(pv[i]);
            aH[i & 3] += ww[i] * bfhi(pv[i]);
        }
    }
    float aLs = (aL[0] + aL[1]) + (aL[2] + aL[3]);
    float aHs = (aH[0] + aH[1]) + (aH[2] + aH[3]);
    if (act) {
        const float2* b1p = (const float2*)b1;
        float2 bb = b1p[l];
        float2 o;
        o.x = aLs / ssum + bb.x;
        o.y = aHs / ssum + bb.y;
        ((float2*)out)[(size_t)node * 20 + l] = o;
    }
}

extern "C" void kernel_launch(void* const* d_in, const int* in_sizes, int n_in,
                              void* d_out, int out_size, void* d_ws, size_t ws_size,
                              hipStream_t stream) {
    const float* x   = (const float*)d_in[0];
    const int*   ei  = (const int*)d_in[1];
    const float* wq0 = (const float*)d_in[2];
    const float* bq0 = (const float*)d_in[3];
    const float* wk0 = (const float*)d_in[4];
    const float* bk0 = (const float*)d_in[5];
    const float* wv0 = (const float*)d_in[6];
    const float* b0  = (const float*)d_in[7];
    const float* wq1 = (const float*)d_in[8];
    const float* bq1 = (const float*)d_in[9];
    const float* wk1 = (const float*)d_in[10];
    const float* bk1 = (const float*)d_in[11];
    const float* wv1 = (const float*)d_in[12];
    const float* b1  = (const float*)d_in[13];
    float* out = (float*)d_out;

    int n    = in_sizes[0] / Fdim;   // 50000
    int E_   = in_sizes[1] / 2;      // 800000
    int Etot = E_ + n;               // + self-loops
    const int* row = ei;
    const int* col = ei + E_;

    float* ws = (float*)d_ws;
    float*          Q0     = ws;                   ws += (size_t)n * 64;
    unsigned int*   KV0    = (unsigned int*)ws;    ws += (size_t)n * 64;
    unsigned short* V1u    = (unsigned short*)ws;  ws += (size_t)n * 20;
    float*          Q1     = ws;                   ws += n;
    float*          K1     = ws;                   ws += n;
    unsigned short* adj    = (unsigned short*)ws;  ws += (size_t)n * (CAP / 2);
    unsigned short* WT     = (unsigned short*)ws;  ws += (192 * Fdim) / 2;
    // ---- small zero region (memset) ----
    int*            cnt    = (int*)ws;             ws += n;
    int*            spillc = (int*)ws;             ws += 4;
    // ---- large zero region (zeroed inside k_node0adj, after scatter) ----
    float*          extra0 = ws;                   ws += (size_t)n * 72;
    float*          extra1 = ws;                   ws += (size_t)n * 44;
    unsigned int*   spill  = (unsigned int*)ws;

    int extra_zero_q = (int)(((size_t)n * 72 + (size_t)n * 44) / 4);
    int ngrid0 = 2048;   // all blocks scatter+zero; first 782 also GEMM

    // --- prep: zero cnt+spillc only; transpose+bf16 weights ---
    hipMemsetAsync(cnt, 0, ((size_t)n + 4) * sizeof(int), stream);
    k_wt<<<(192 * Fdim + 255) / 256, 256, 0, stream>>>(wq0, wk0, wv0, WT);

    // --- MFMA node0 GEMM + adjacency build + zeroing in one kernel ---
    k_node0adj<<<ngrid0, 256, 0, stream>>>(x, WT, bq0, bk0, Q0, KV0,
                                           row, col, cnt, adj,
                                           spill, spillc,
                                           (float4*)extra0, extra_zero_q,
                                           E_, Etot, n);
    k_spill0<<<64, 256, 0, stream>>>(spillc, spill, Q0, KV0, extra0);

    // --- Layer 0 fused (+ layer-1 node transform epilogue) ---
    k_fuse0<<<(n + 7) / 8, 256, 0, stream>>>(cnt, adj, Q0, KV0, extra0, spillc, b0,
                                             wq1, bq1, wk1, bk1, wv1,
                                             Q1, K1, V1u, n);
    k_spill1<<<64, 256, 0, stream>>>(spillc, spill, Q1, K1, V1u, extra1);

    // --- Layer 1 fused ---
    k_fuse1<<<(n + 7) / 8, 256, 0, stream>>>(cnt, adj, Q1, K1,
                                             (const unsigned int*)V1u, extra1,
                                             spillc, b1, out, n);
}